// Round 8
// baseline (208.514 us; speedup 1.0000x reference)
//
#include <hip/hip_runtime.h>
#include <hip/hip_bf16.h>

#define NIN 1024
#define NOUT 4096
#define NTOK 4096
#define NSTACK 4
#define RANK 4

typedef __bf16 bf16x8 __attribute__((ext_vector_type(8)));
typedef float f32x4 __attribute__((ext_vector_type(4)));

// ============ fused prep ============
// blocks 0..1023: build M. block = (stack s, band of 32 diagonals, chunk of 256 rows).
//   Wave owns 8 diagonals: recompute chunk carry (t < t0) via lane-strided sum +
//   shfl_xor reduce, then one flat 6-shfl scan over the 256-row chunk (lane owns
//   4 rows), stage bf16 into padded LDS parallelogram, cooperative coalesced store
//   of 32-col row segments (full/half cache lines — kills the 9x write amp of R6).
// blocks 1024..3071: cast x fp32->bf16.
//
// M[s,t,c] = prefix along diagonal of E[t][c] = sum_r G_r[t]*H_r[c].
__global__ __launch_bounds__(256) void prep_kernel(const float* __restrict__ x,
                                                   const float* __restrict__ G,
                                                   const float* __restrict__ H,
                                                   __bf16* __restrict__ xb,
                                                   __bf16* __restrict__ M) {
  __shared__ unsigned short tile[256][33];  // padded: 2-way max bank aliasing
  int bid = blockIdx.x;
  if (bid >= 1024) {  // -------- cast --------
    int i = ((bid - 1024) * 256 + threadIdx.x) * 8;
    float4 a = *reinterpret_cast<const float4*>(x + i);
    float4 b = *reinterpret_cast<const float4*>(x + i + 4);
    bf16x8 o;
    o[0] = (__bf16)a.x; o[1] = (__bf16)a.y; o[2] = (__bf16)a.z; o[3] = (__bf16)a.w;
    o[4] = (__bf16)b.x; o[5] = (__bf16)b.y; o[6] = (__bf16)b.z; o[7] = (__bf16)b.w;
    *reinterpret_cast<bf16x8*>(xb + i) = o;
    return;
  }
  // -------- build M --------
  const int s = bid >> 8;            // stack
  const int band = (bid >> 2) & 63;  // 32-diagonal band
  const int g = bid & 3;             // 256-row chunk
  const int t0 = g * 256;
  const int w = threadIdx.x >> 6;
  const int lane = threadIdx.x & 63;
  const float* Gs = G + s * (RANK * NIN);
  const float* Hs = H + s * (RANK * NIN);
  unsigned short* Ms = (unsigned short*)(M + (size_t)s * NIN * NIN);
  const int cbase = band * 32 - 1023;  // c = t + cbase + j, j in [0,32)

  #pragma unroll 1
  for (int j8 = 0; j8 < 8; ++j8) {
    const int j = w * 8 + j8;
    const int doff = cbase + j;        // c = t + doff
    // ---- carry: sum over rows t < t0 (redundant recompute; VALU is idle) ----
    float carry = 0.f;
    for (int tb = 0; tb < t0; tb += 64) {
      const int t = tb + lane;
      const int c = t + doff;
      if ((unsigned)c < (unsigned)NIN)
        carry += Gs[t] * Hs[c] + Gs[NIN + t] * Hs[NIN + c]
               + Gs[2 * NIN + t] * Hs[2 * NIN + c] + Gs[3 * NIN + t] * Hs[3 * NIN + c];
    }
    #pragma unroll
    for (int off = 32; off; off >>= 1) carry += __shfl_xor(carry, off, 64);
    // ---- chunk scan: lane owns rows t0 + lane*4 .. +3 ----
    float e[4];
    float ssum = 0.f;
    #pragma unroll
    for (int i = 0; i < 4; ++i) {
      const int t = t0 + lane * 4 + i;
      const int c = t + doff;
      float v = 0.f;
      if ((unsigned)c < (unsigned)NIN)
        v = Gs[t] * Hs[c] + Gs[NIN + t] * Hs[NIN + c]
          + Gs[2 * NIN + t] * Hs[2 * NIN + c] + Gs[3 * NIN + t] * Hs[3 * NIN + c];
      e[i] = v;
      ssum += v;
    }
    float incl = ssum;
    #pragma unroll
    for (int off = 1; off < 64; off <<= 1) {
      float o = __shfl_up(incl, off, 64);
      if (lane >= off) incl += o;
    }
    float acc = carry + incl - ssum;  // carry + exclusive prefix
    #pragma unroll
    for (int i = 0; i < 4; ++i) {
      const int r = lane * 4 + i;
      const int c = t0 + r + doff;
      acc += e[i];
      if ((unsigned)c < (unsigned)NIN) {
        __bf16 b = (__bf16)acc;
        tile[r][j] = *(const unsigned short*)&b;
      }
    }
  }
  __syncthreads();
  // ---- cooperative store: contiguous 32-col row segments ----
  #pragma unroll 1
  for (int p = 0; p < 32; ++p) {
    const int idx = p * 256 + threadIdx.x;
    const int r = idx >> 5, j = idx & 31;
    const int t = t0 + r;
    const int c = t + cbase + j;
    if ((unsigned)c < (unsigned)NIN)
      Ms[(size_t)t * NIN + c] = tile[r][j];
  }
}

// ============ GEMM: C[m][n] = sum_k A[m][k]*B[n][k] + bias[n] ============
// (byte-identical to round 5)
#define GBK 64
#define GKT (NIN / GBK)     // 16
#define BUFSZ 32768         // A 16K + B 16K

__device__ __forceinline__ void gload16(const char* gsrc, char* lds) {
  __builtin_amdgcn_global_load_lds(
      (const __attribute__((address_space(1))) unsigned int*)gsrc,
      (__attribute__((address_space(3))) unsigned int*)lds, 16, 0, 0);
}

__global__ __launch_bounds__(256, 2) void gemm_kernel(
    const __bf16* __restrict__ A,   // [NTOK][NIN]
    const __bf16* __restrict__ B,   // [NOUT][NIN]
    const float* __restrict__ bias, // [NOUT]
    float* __restrict__ C) {        // [NTOK][NOUT]
  __shared__ __align__(16) char smem[2 * BUFSZ];  // 64 KB

  const int tid = threadIdx.x;
  const int lane = tid & 63;
  const int lo = lane & 15;
  const int hi = lane >> 4;
  const int wid = tid >> 6;
  const int wr = wid >> 1;   // 0..1
  const int wc = wid & 1;    // 0..1

  // XCD-aware swizzle (grid 1024, 1024%8==0)
  const int orig = blockIdx.x;
  const int wg = (orig & 7) * 128 + (orig >> 3);
  const int bx = wg & 31;
  const int by = wg >> 5;
  const int brow = by * 128;
  const int bcol = bx * 128;

  const char* Ab = (const char*)A + (size_t)brow * (NIN * 2);
  const char* Bb = (const char*)B + (size_t)bcol * (NIN * 2);

  // staging: per thread 4 A + 4 B gloads per K-tile. LDS dest linear;
  // global source pre-swizzled: inner ^ ((row&7)<<4)  [both-sides rule 21]
  int lofs[4];
  size_t gofs2[4];
  #pragma unroll
  for (int l = 0; l < 4; ++l) {
    const int P = tid * 16 + l * 4096;   // 0..16383
    const int row = P >> 7;              // 0..127
    const int inner = (P & 127) ^ ((row & 7) << 4);
    lofs[l] = P;
    gofs2[l] = (size_t)row * (NIN * 2) + inner;
  }

  // fragment ds_read byte offsets (swizzled read side), row&7 == lo&7
  int aoff[4][2], boff[4][2];
  #pragma unroll
  for (int mi = 0; mi < 4; ++mi)
    #pragma unroll
    for (int ks = 0; ks < 2; ++ks) {
      const int kin = (ks * 64 + hi * 16) ^ ((lo & 7) << 4);
      aoff[mi][ks] = (wr * 64 + mi * 16 + lo) * 128 + kin;
      boff[mi][ks] = 16384 + (wc * 64 + mi * 16 + lo) * 128 + kin;
    }

  f32x4 acc[4][4];
  #pragma unroll
  for (int i = 0; i < 4; ++i)
    #pragma unroll
    for (int j = 0; j < 4; ++j)
      acc[i][j] = (f32x4){0.f, 0.f, 0.f, 0.f};

  // prologue: stage tile 0 -> buf 0
  #pragma unroll
  for (int l = 0; l < 4; ++l) gload16(Ab + gofs2[l], smem + lofs[l]);
  #pragma unroll
  for (int l = 0; l < 4; ++l) gload16(Bb + gofs2[l], smem + 16384 + lofs[l]);

  #pragma unroll 1
  for (int kt = 0; kt < GKT; ++kt) {
    // stage next tile (safe: all waves passed bottom barrier of kt-1,
    // which guaranteed reads of buf^1 (tile kt-1) were complete)
    if (kt < GKT - 1) {
      char* sb = smem + ((kt + 1) & 1) * BUFSZ;
      const int kb = (kt + 1) * 128;
      #pragma unroll
      for (int l = 0; l < 4; ++l) gload16(Ab + kb + gofs2[l], sb + lofs[l]);
      #pragma unroll
      for (int l = 0; l < 4; ++l) gload16(Bb + kb + gofs2[l], sb + 16384 + lofs[l]);
      asm volatile("s_waitcnt vmcnt(8)" ::: "memory");  // tile kt resident
    } else {
      asm volatile("s_waitcnt vmcnt(0)" ::: "memory");
    }
    __builtin_amdgcn_s_barrier();

    const char* buf = smem + (kt & 1) * BUFSZ;
    #pragma unroll
    for (int ks = 0; ks < 2; ++ks) {
      bf16x8 af[4], bfr[4];
      #pragma unroll
      for (int mi = 0; mi < 4; ++mi)
        af[mi] = *(const bf16x8*)(buf + aoff[mi][ks]);
      #pragma unroll
      for (int ni = 0; ni < 4; ++ni)
        bfr[ni] = *(const bf16x8*)(buf + boff[ni][ks]);
      __builtin_amdgcn_s_setprio(1);
      #pragma unroll
      for (int mi = 0; mi < 4; ++mi)
        #pragma unroll
        for (int ni = 0; ni < 4; ++ni)
          acc[mi][ni] = __builtin_amdgcn_mfma_f32_16x16x32_bf16(af[mi], bfr[ni], acc[mi][ni], 0, 0, 0);
      __builtin_amdgcn_s_setprio(0);
    }
    __builtin_amdgcn_s_barrier();
  }

  // epilogue: D layout col=lane&15, row=(lane>>4)*4+reg
  #pragma unroll
  for (int ni = 0; ni < 4; ++ni) {
    const int col = bcol + wc * 64 + ni * 16 + lo;
    const float bv = bias[col];
    #pragma unroll
    for (int mi = 0; mi < 4; ++mi) {
      const int row0 = brow + wr * 64 + mi * 16 + hi * 4;
      float* Cp = C + (size_t)row0 * NOUT + col;
      Cp[0]                = acc[mi][ni][0] + bv;
      Cp[(size_t)NOUT]     = acc[mi][ni][1] + bv;
      Cp[2 * (size_t)NOUT] = acc[mi][ni][2] + bv;
      Cp[3 * (size_t)NOUT] = acc[mi][ni][3] + bv;
    }
  }
}

extern "C" void kernel_launch(void* const* d_in, const int* in_sizes, int n_in,
                              void* d_out, int out_size, void* d_ws, size_t ws_size,
                              hipStream_t stream) {
  const float* x = (const float*)d_in[0];
  const float* G = (const float*)d_in[1];
  const float* H = (const float*)d_in[2];
  const float* bias = (const float*)d_in[3];
  float* out = (float*)d_out;

  __bf16* xb = (__bf16*)d_ws;                                    // 8 MB
  __bf16* Mb = (__bf16*)((char*)d_ws + (size_t)NTOK * NIN * 2);  // 8 MB

  prep_kernel<<<1024 + 2048, 256, 0, stream>>>(x, G, H, xb, Mb);
  gemm_kernel<<<1024, 256, 0, stream>>>(xb, Mb, bias, out);
}

// Round 9
// 158.747 us; speedup vs baseline: 1.3135x; 1.3135x over previous
//
#include <hip/hip_runtime.h>
#include <hip/hip_bf16.h>

#define NIN 1024
#define NOUT 4096
#define NTOK 4096
#define NSTACK 4
#define RANK 4

typedef __bf16 bf16x8 __attribute__((ext_vector_type(8)));
typedef float f32x4 __attribute__((ext_vector_type(4)));

// ============ prep: hierarchical diagonal prefix, band-row-walk form ============
// Band b (64 consecutive diagonals, Wb = 64b-1024), lane = diagonal-in-band.
// Walking rows t: G[t] is wave-uniform (scalar load), H[t+Wb+lane] is
// lane-consecutive (coalesced), and the 64 results store to
// M[t][t+Wb .. t+Wb+63] = one contiguous 128-B wave store. No shfl/LDS/barriers;
// serial chain = 1 add/row. Chunks of 64 rows -> 2048 independent waves.
// prepA: per-chunk diagonal sums S[s][band][q][lane] (fp32, stored in d_out tail).
// prepB: carry = sum of earlier chunk-sums (<=15 coalesced loads), then walk
// 64 rows, accumulate, store bf16. Order along each diagonal is exactly
// sequential -> bit-identical M to prior rounds.

__global__ __launch_bounds__(256) void prepA_kernel(const float* __restrict__ x,
                                                    const float* __restrict__ G,
                                                    const float* __restrict__ H,
                                                    __bf16* __restrict__ xb,
                                                    float* __restrict__ S) {
  int bid = blockIdx.x;
  if (bid >= 512) {  // -------- cast: 2048 blocks --------
    int i = ((bid - 512) * 256 + threadIdx.x) * 8;
    float4 a = *reinterpret_cast<const float4*>(x + i);
    float4 b = *reinterpret_cast<const float4*>(x + i + 4);
    bf16x8 o;
    o[0] = (__bf16)a.x; o[1] = (__bf16)a.y; o[2] = (__bf16)a.z; o[3] = (__bf16)a.w;
    o[4] = (__bf16)b.x; o[5] = (__bf16)b.y; o[6] = (__bf16)b.z; o[7] = (__bf16)b.w;
    *reinterpret_cast<bf16x8*>(xb + i) = o;
    return;
  }
  // -------- chunk sums: block = (s, band, qg); wave = chunk q --------
  const int s = bid >> 7;
  const int band = (bid >> 2) & 31;
  const int qg = bid & 3;
  const int q = qg * 4 + (threadIdx.x >> 6);   // 0..15
  const int lane = threadIdx.x & 63;
  const int Wb = band * 64 - 1024;
  const float* Gs = G + s * (RANK * NIN);
  const float* Hs = H + s * (RANK * NIN);

  int tmin = -Wb - 63; if (tmin < 0) tmin = 0;
  int tmax = 1023 - Wb; if (tmax > 1023) tmax = 1023;
  int t0 = q * 64, t1 = q * 64 + 64;
  if (t0 < tmin) t0 = tmin;
  if (t1 > tmax + 1) t1 = tmax + 1;

  float acc = 0.f;
  int c = t0 + Wb + lane;
  for (int t = t0; t < t1; ++t, ++c) {
    if ((unsigned)c < 1024u)
      acc += Gs[t] * Hs[c] + Gs[NIN + t] * Hs[NIN + c]
           + Gs[2 * NIN + t] * Hs[2 * NIN + c] + Gs[3 * NIN + t] * Hs[3 * NIN + c];
  }
  S[(((s * 32 + band) * 16) + q) * 64 + lane] = acc;
}

__global__ __launch_bounds__(256) void prepB_kernel(const float* __restrict__ G,
                                                    const float* __restrict__ H,
                                                    const float* __restrict__ S,
                                                    __bf16* __restrict__ M) {
  const int bid = blockIdx.x;  // 512 blocks
  const int s = bid >> 7;
  const int band = (bid >> 2) & 31;
  const int qg = bid & 3;
  const int q = qg * 4 + (threadIdx.x >> 6);   // 0..15
  const int lane = threadIdx.x & 63;
  const int Wb = band * 64 - 1024;
  const float* Gs = G + s * (RANK * NIN);
  const float* Hs = H + s * (RANK * NIN);
  __bf16* Ms = M + (size_t)s * NIN * NIN;

  // carry: sum of earlier chunks' diagonal sums (coalesced 256-B loads)
  const float* Sp = S + ((s * 32 + band) * 16) * 64 + lane;
  float acc = 0.f;
  for (int qq = 0; qq < q; ++qq) acc += Sp[qq * 64];

  int tmin = -Wb - 63; if (tmin < 0) tmin = 0;
  int tmax = 1023 - Wb; if (tmax > 1023) tmax = 1023;
  int t0 = q * 64, t1 = q * 64 + 64;
  if (t0 < tmin) t0 = tmin;
  if (t1 > tmax + 1) t1 = tmax + 1;

  int c = t0 + Wb + lane;
  for (int t = t0; t < t1; ++t, ++c) {
    if ((unsigned)c < 1024u) {
      acc += Gs[t] * Hs[c] + Gs[NIN + t] * Hs[NIN + c]
           + Gs[2 * NIN + t] * Hs[2 * NIN + c] + Gs[3 * NIN + t] * Hs[3 * NIN + c];
      Ms[(size_t)t * NIN + c] = (__bf16)acc;   // 64 lanes -> contiguous 128 B
    }
  }
}

// ============ GEMM: C[m][n] = sum_k A[m][k]*B[n][k] + bias[n] ============
// (byte-identical to rounds 5-8)
#define GBK 64
#define GKT (NIN / GBK)     // 16
#define BUFSZ 32768         // A 16K + B 16K

__device__ __forceinline__ void gload16(const char* gsrc, char* lds) {
  __builtin_amdgcn_global_load_lds(
      (const __attribute__((address_space(1))) unsigned int*)gsrc,
      (__attribute__((address_space(3))) unsigned int*)lds, 16, 0, 0);
}

__global__ __launch_bounds__(256, 2) void gemm_kernel(
    const __bf16* __restrict__ A,   // [NTOK][NIN]
    const __bf16* __restrict__ B,   // [NOUT][NIN]
    const float* __restrict__ bias, // [NOUT]
    float* __restrict__ C) {        // [NTOK][NOUT]
  __shared__ __align__(16) char smem[2 * BUFSZ];  // 64 KB

  const int tid = threadIdx.x;
  const int lane = tid & 63;
  const int lo = lane & 15;
  const int hi = lane >> 4;
  const int wid = tid >> 6;
  const int wr = wid >> 1;   // 0..1
  const int wc = wid & 1;    // 0..1

  // XCD-aware swizzle (grid 1024, 1024%8==0)
  const int orig = blockIdx.x;
  const int wg = (orig & 7) * 128 + (orig >> 3);
  const int bx = wg & 31;
  const int by = wg >> 5;
  const int brow = by * 128;
  const int bcol = bx * 128;

  const char* Ab = (const char*)A + (size_t)brow * (NIN * 2);
  const char* Bb = (const char*)B + (size_t)bcol * (NIN * 2);

  // staging: per thread 4 A + 4 B gloads per K-tile. LDS dest linear;
  // global source pre-swizzled: inner ^ ((row&7)<<4)  [both-sides rule 21]
  int lofs[4];
  size_t gofs2[4];
  #pragma unroll
  for (int l = 0; l < 4; ++l) {
    const int P = tid * 16 + l * 4096;   // 0..16383
    const int row = P >> 7;              // 0..127
    const int inner = (P & 127) ^ ((row & 7) << 4);
    lofs[l] = P;
    gofs2[l] = (size_t)row * (NIN * 2) + inner;
  }

  // fragment ds_read byte offsets (swizzled read side), row&7 == lo&7
  int aoff[4][2], boff[4][2];
  #pragma unroll
  for (int mi = 0; mi < 4; ++mi)
    #pragma unroll
    for (int ks = 0; ks < 2; ++ks) {
      const int kin = (ks * 64 + hi * 16) ^ ((lo & 7) << 4);
      aoff[mi][ks] = (wr * 64 + mi * 16 + lo) * 128 + kin;
      boff[mi][ks] = 16384 + (wc * 64 + mi * 16 + lo) * 128 + kin;
    }

  f32x4 acc[4][4];
  #pragma unroll
  for (int i = 0; i < 4; ++i)
    #pragma unroll
    for (int j = 0; j < 4; ++j)
      acc[i][j] = (f32x4){0.f, 0.f, 0.f, 0.f};

  // prologue: stage tile 0 -> buf 0
  #pragma unroll
  for (int l = 0; l < 4; ++l) gload16(Ab + gofs2[l], smem + lofs[l]);
  #pragma unroll
  for (int l = 0; l < 4; ++l) gload16(Bb + gofs2[l], smem + 16384 + lofs[l]);

  #pragma unroll 1
  for (int kt = 0; kt < GKT; ++kt) {
    if (kt < GKT - 1) {
      char* sb = smem + ((kt + 1) & 1) * BUFSZ;
      const int kb = (kt + 1) * 128;
      #pragma unroll
      for (int l = 0; l < 4; ++l) gload16(Ab + kb + gofs2[l], sb + lofs[l]);
      #pragma unroll
      for (int l = 0; l < 4; ++l) gload16(Bb + kb + gofs2[l], sb + 16384 + lofs[l]);
      asm volatile("s_waitcnt vmcnt(8)" ::: "memory");  // tile kt resident
    } else {
      asm volatile("s_waitcnt vmcnt(0)" ::: "memory");
    }
    __builtin_amdgcn_s_barrier();

    const char* buf = smem + (kt & 1) * BUFSZ;
    #pragma unroll
    for (int ks = 0; ks < 2; ++ks) {
      bf16x8 af[4], bfr[4];
      #pragma unroll
      for (int mi = 0; mi < 4; ++mi)
        af[mi] = *(const bf16x8*)(buf + aoff[mi][ks]);
      #pragma unroll
      for (int ni = 0; ni < 4; ++ni)
        bfr[ni] = *(const bf16x8*)(buf + boff[ni][ks]);
      __builtin_amdgcn_s_setprio(1);
      #pragma unroll
      for (int mi = 0; mi < 4; ++mi)
        #pragma unroll
        for (int ni = 0; ni < 4; ++ni)
          acc[mi][ni] = __builtin_amdgcn_mfma_f32_16x16x32_bf16(af[mi], bfr[ni], acc[mi][ni], 0, 0, 0);
      __builtin_amdgcn_s_setprio(0);
    }
    __builtin_amdgcn_s_barrier();
  }

  // epilogue: D layout col=lane&15, row=(lane>>4)*4+reg
  #pragma unroll
  for (int ni = 0; ni < 4; ++ni) {
    const int col = bcol + wc * 64 + ni * 16 + lo;
    const float bv = bias[col];
    #pragma unroll
    for (int mi = 0; mi < 4; ++mi) {
      const int row0 = brow + wr * 64 + mi * 16 + hi * 4;
      float* Cp = C + (size_t)row0 * NOUT + col;
      Cp[0]                = acc[mi][ni][0] + bv;
      Cp[(size_t)NOUT]     = acc[mi][ni][1] + bv;
      Cp[2 * (size_t)NOUT] = acc[mi][ni][2] + bv;
      Cp[3 * (size_t)NOUT] = acc[mi][ni][3] + bv;
    }
  }
}

extern "C" void kernel_launch(void* const* d_in, const int* in_sizes, int n_in,
                              void* d_out, int out_size, void* d_ws, size_t ws_size,
                              hipStream_t stream) {
  const float* x = (const float*)d_in[0];
  const float* G = (const float*)d_in[1];
  const float* H = (const float*)d_in[2];
  const float* bias = (const float*)d_in[3];
  float* out = (float*)d_out;

  __bf16* xb = (__bf16*)d_ws;                                    // 8 MB
  __bf16* Mb = (__bf16*)((char*)d_ws + (size_t)NTOK * NIN * 2);  // 8 MB
  // S (chunk sums, 512 KB fp32) lives in d_out's tail: consumed by prepB
  // before gemm overwrites all of d_out. Zero extra ws usage.
  float* S = out + (size_t)NTOK * NOUT - 4 * 32 * 16 * 64;

  prepA_kernel<<<512 + 2048, 256, 0, stream>>>(x, G, H, xb, S);
  prepB_kernel<<<512, 256, 0, stream>>>(G, H, S, Mb);
  gemm_kernel<<<1024, 256, 0, stream>>>(xb, Mb, bias, out);
}